// Round 2
// baseline (674.345 us; speedup 1.0000x reference)
//
#include <hip/hip_runtime.h>
#include <hip/hip_bf16.h>
#include <cmath>

#define T_SEQ 2048
#define NHEADS 16
#define DHEAD 64
#define DMODEL 1024
#define CQKV 3072

typedef __attribute__((ext_vector_type(8))) short short8;
typedef __attribute__((ext_vector_type(8))) __bf16 bf16x8;
typedef __attribute__((ext_vector_type(4))) float floatx4;

static __device__ __forceinline__ floatx4 mfma_bf16(short8 a, short8 b, floatx4 c) {
  return __builtin_amdgcn_mfma_f32_16x16x32_bf16(
      __builtin_bit_cast(bf16x8, a), __builtin_bit_cast(bf16x8, b), c, 0, 0, 0);
}

// fp32 -> bf16 round-to-nearest-even, bit carrier = short
static __device__ __forceinline__ short f2bf(float f) {
  union { float f; unsigned u; } x; x.f = f;
  unsigned r = x.u + 0x7FFFu + ((x.u >> 16) & 1u);
  return (short)(r >> 16);
}

// Decide whether the input buffers are bf16 or fp32 by inspecting the low
// 16 bits of the first 32 words of x. bf16 data: low short is a ~N(0,1)
// bf16 (exponent near 127). fp32 data: low short = mantissa garbage
// (exponent uniform over 0..255, in-range p=0.125). 16-of-32 vote.
static __device__ __forceinline__ bool sniff_is_bf16(const unsigned* __restrict__ x) {
  int cnt = 0;
#pragma unroll
  for (int i = 0; i < 32; ++i) {
    unsigned e = (x[i] >> 7) & 0xFFu;
    cnt += (e >= 0x70u && e <= 0x8Fu) ? 1 : 0;
  }
  return cnt >= 16;
}

// Load 8 consecutive elements (element index idx) as bf16 bits.
static __device__ __forceinline__ short8 load8(const char* p, size_t idx, bool isbf) {
  if (isbf) return *(const short8*)(p + idx * 2);
  const float4* f = (const float4*)(p + idx * 4);
  float4 a = f[0], b = f[1];
  short8 r;
  r[0] = f2bf(a.x); r[1] = f2bf(a.y); r[2] = f2bf(a.z); r[3] = f2bf(a.w);
  r[4] = f2bf(b.x); r[5] = f2bf(b.y); r[6] = f2bf(b.z); r[7] = f2bf(b.w);
  return r;
}

// C[M,N] = A[M,K] @ B[K,N]; fp32 accum; per-operand dtype chosen at runtime.
// AF/BF/CF: operand follows the sniffed input dtype; false -> always bf16 (ws).
// 64x64 tile, BK=32, 256 threads = 4 waves.
template <bool AF, bool BF, bool CF>
__global__ __launch_bounds__(256) void gemm64t(const char* __restrict__ A,
                                               const char* __restrict__ B,
                                               char* __restrict__ C,
                                               int M, int N, int K,
                                               const unsigned* __restrict__ xs) {
  const bool dynbf = (AF || BF || CF) ? sniff_is_bf16(xs) : true;
  const bool abf = AF ? dynbf : true;
  const bool bbf = BF ? dynbf : true;
  const bool cbf = CF ? dynbf : true;

  __shared__ short as[64][40];   // [m][k]
  __shared__ short bst[64][40];  // [n][k] (B transposed)
  const int tid = threadIdx.x;
  const int wid = tid >> 6, lane = tid & 63;
  const int quad = lane >> 4, l16 = lane & 15;
  const int m0 = blockIdx.y * 64, n0 = blockIdx.x * 64;

  const int arow = tid >> 2, akc = (tid & 3) * 8;  // A stage: 64 rows x 32k
  const int bk = tid >> 3, bn = (tid & 7) * 8;     // B stage: 32k x 64n

  const floatx4 zero4 = {0.f, 0.f, 0.f, 0.f};
  floatx4 acc[4];
#pragma unroll
  for (int i = 0; i < 4; ++i) acc[i] = zero4;

  for (int kt = 0; kt < K; kt += 32) {
    __syncthreads();
    *(short8*)&as[arow][akc] = load8(A, (size_t)(m0 + arow) * K + kt + akc, abf);
    short8 bv = load8(B, (size_t)(kt + bk) * N + n0 + bn, bbf);
#pragma unroll
    for (int j = 0; j < 8; ++j) bst[bn + j][bk] = bv[j];
    __syncthreads();

    short8 af = *(const short8*)&as[wid * 16 + l16][quad * 8];
#pragma unroll
    for (int nt = 0; nt < 4; ++nt) {
      short8 bfr = *(const short8*)&bst[nt * 16 + l16][quad * 8];
      acc[nt] = mfma_bf16(af, bfr, acc[nt]);
    }
  }

  const int row = m0 + wid * 16 + quad * 4;
#pragma unroll
  for (int nt = 0; nt < 4; ++nt) {
    const int col = n0 + nt * 16 + l16;
#pragma unroll
    for (int r = 0; r < 4; ++r) {
      const size_t off = (size_t)(row + r) * N + col;
      if (cbf) ((short*)C)[off] = f2bf(acc[nt][r]);
      else     ((float*)C)[off] = acc[nt][r];
    }
  }
}

// Flash-style causal attention over qkv[b, t, which*1024 + h*64 + d] (bf16 ws).
// Block = 256 thr = 4 waves; block covers 64 queries (16/wave), K-tiles of 32.
__global__ __launch_bounds__(256) void attn(const short* __restrict__ qkv,
                                            short* __restrict__ y) {
  __shared__ short vt[64][40];     // V^T tile: [d][key]
  __shared__ short ps[4][16][40];  // per-wave P: [q][key]
  const int tid = threadIdx.x;
  const int wid = tid >> 6, lane = tid & 63;
  const int quad = lane >> 4, l16 = lane & 15;
  const int b = blockIdx.x >> 4, h = blockIdx.x & 15;
  const int q0 = blockIdx.y * 64;
  const int qw0 = q0 + wid * 16;

  const short* base = qkv + (size_t)b * T_SEQ * CQKV + h * DHEAD;

  // Q fragments (A-layout): m=lane&15 (query), k=quad*8+j (d), 2 chunks of 32
  short8 aq[2];
#pragma unroll
  for (int kc = 0; kc < 2; ++kc)
    aq[kc] = *(const short8*)(base + (size_t)(qw0 + l16) * CQKV + kc * 32 + quad * 8);

  const floatx4 zero4 = {0.f, 0.f, 0.f, 0.f};
  floatx4 o[4];
#pragma unroll
  for (int i = 0; i < 4; ++i) o[i] = zero4;
  float mrow[4] = {-INFINITY, -INFINITY, -INFINITY, -INFINITY};
  float lrow[4] = {0.f, 0.f, 0.f, 0.f};

  const int vkey = tid >> 3, vd = (tid & 7) * 8;
  const int kend = q0 + 64;  // keys 0 .. q0+63 (extra keys masked per-row)

  for (int kt = 0; kt < kend; kt += 32) {
    __syncthreads();  // protect vt from previous iteration's readers
    {
      short8 vv = *(const short8*)(base + (size_t)(kt + vkey) * CQKV + 2 * DMODEL + vd);
#pragma unroll
      for (int j = 0; j < 8; ++j) vt[vd + j][vkey] = vv[j];
    }
    __syncthreads();

    // S = Q K^T  (16q x 32keys per wave): B-frag = K rows straight from global
    floatx4 s[2] = {zero4, zero4};
#pragma unroll
    for (int nt = 0; nt < 2; ++nt)
#pragma unroll
      for (int kc = 0; kc < 2; ++kc) {
        short8 bkf = *(const short8*)(base + (size_t)(kt + nt * 16 + l16) * CQKV +
                                      DMODEL + kc * 32 + quad * 8);
        s[nt] = mfma_bf16(aq[kc], bkf, s[nt]);
      }

    // scale + causal mask (C layout: row q = quad*4+r, col key = nt*16+l16)
#pragma unroll
    for (int nt = 0; nt < 2; ++nt)
#pragma unroll
      for (int r = 0; r < 4; ++r) {
        const int key = kt + nt * 16 + l16;
        const int q = qw0 + quad * 4 + r;
        const float v = s[nt][r] * 0.125f;
        s[nt][r] = (key <= q) ? v : -INFINITY;
      }

    // online softmax: row r lives in the 16 lanes of one quad -> width-16 shfl
    float alpha[4];
#pragma unroll
    for (int r = 0; r < 4; ++r) {
      float mx = fmaxf(s[0][r], s[1][r]);
      mx = fmaxf(mx, __shfl_xor(mx, 1, 16));
      mx = fmaxf(mx, __shfl_xor(mx, 2, 16));
      mx = fmaxf(mx, __shfl_xor(mx, 4, 16));
      mx = fmaxf(mx, __shfl_xor(mx, 8, 16));
      const float nm = fmaxf(mrow[r], mx);  // finite after tile 0 (key 0 valid)
      alpha[r] = __expf(mrow[r] - nm);
      mrow[r] = nm;
    }
#pragma unroll
    for (int nt = 0; nt < 2; ++nt)
#pragma unroll
      for (int r = 0; r < 4; ++r)
        s[nt][r] = __expf(s[nt][r] - mrow[r]);  // masked -> exp(-inf)=0

#pragma unroll
    for (int r = 0; r < 4; ++r) {
      float rs = s[0][r] + s[1][r];
      rs += __shfl_xor(rs, 1, 16);
      rs += __shfl_xor(rs, 2, 16);
      rs += __shfl_xor(rs, 4, 16);
      rs += __shfl_xor(rs, 8, 16);
      lrow[r] = lrow[r] * alpha[r] + rs;
    }

#pragma unroll
    for (int d4 = 0; d4 < 4; ++d4)
#pragma unroll
      for (int r = 0; r < 4; ++r) o[d4][r] *= alpha[r];

    // P: C-layout -> LDS -> A-layout (documented correct transform)
#pragma unroll
    for (int nt = 0; nt < 2; ++nt)
#pragma unroll
      for (int r = 0; r < 4; ++r)
        ps[wid][quad * 4 + r][nt * 16 + l16] = f2bf(s[nt][r]);

    __syncthreads();

    short8 ap = *(const short8*)&ps[wid][l16][quad * 8];
#pragma unroll
    for (int d4 = 0; d4 < 4; ++d4) {
      short8 bvf = *(const short8*)&vt[d4 * 16 + l16][quad * 8];
      o[d4] = mfma_bf16(ap, bvf, o[d4]);
    }
  }

  // epilogue: O /= l, write y[b, q, h*64 + d]
#pragma unroll
  for (int d4 = 0; d4 < 4; ++d4)
#pragma unroll
    for (int r = 0; r < 4; ++r) {
      const int q = qw0 + quad * 4 + r;
      y[(size_t)(b * T_SEQ + q) * DMODEL + h * DHEAD + d4 * 16 + l16] =
          f2bf(o[d4][r] / lrow[r]);
    }
}

extern "C" void kernel_launch(void* const* d_in, const int* in_sizes, int n_in,
                              void* d_out, int out_size, void* d_ws, size_t ws_size,
                              hipStream_t stream) {
  const char* x = (const char*)d_in[0];       // [4,2048,1024] fp32 or bf16
  const char* w_qkv = (const char*)d_in[1];   // [1024,3072]
  const char* w_proj = (const char*)d_in[2];  // [1024,1024]
  const unsigned* xs = (const unsigned*)d_in[0];

  short* qkv = (short*)d_ws;                  // 8192*3072 bf16 = 50.3 MB
  short* ybuf = qkv + (size_t)8192 * 3072;    // 8192*1024 bf16 = 16.8 MB

  // 1) qkv = x @ w_qkv   (M=8192, N=3072, K=1024); inputs flagged, out bf16 ws
  {
    dim3 grid(3072 / 64, 8192 / 64);
    gemm64t<true, true, false><<<grid, 256, 0, stream>>>(
        x, w_qkv, (char*)qkv, 8192, 3072, 1024, xs);
  }
  // 2) attention (pure bf16 ws -> ws)
  {
    dim3 grid(4 * NHEADS, T_SEQ / 64);
    attn<<<grid, 256, 0, stream>>>(qkv, ybuf);
  }
  // 3) out = y @ w_proj  (M=8192, N=1024, K=1024); A bf16 ws, B/C flagged
  {
    dim3 grid(1024 / 64, 8192 / 64);
    gemm64t<false, true, true><<<grid, 256, 0, stream>>>(
        (const char*)ybuf, w_proj, (char*)d_out, 8192, 1024, 1024, xs);
  }
}

// Round 3
// 456.594 us; speedup vs baseline: 1.4769x; 1.4769x over previous
//
#include <hip/hip_runtime.h>
#include <hip/hip_bf16.h>
#include <cmath>

#define T_SEQ 2048
#define NHEADS 16
#define DHEAD 64
#define DMODEL 1024
#define CQKV 3072

typedef __attribute__((ext_vector_type(8))) short short8;
typedef __attribute__((ext_vector_type(8))) __bf16 bf16x8;
typedef __attribute__((ext_vector_type(4))) float floatx4;

#define LDS_CAST(p) ((__attribute__((address_space(3))) void*)(p))
#define GLB_CAST(p) ((const __attribute__((address_space(1))) void*)(p))

static __device__ __forceinline__ floatx4 mfma_bf16(short8 a, short8 b, floatx4 c) {
  return __builtin_amdgcn_mfma_f32_16x16x32_bf16(
      __builtin_bit_cast(bf16x8, a), __builtin_bit_cast(bf16x8, b), c, 0, 0, 0);
}

// fp32 -> bf16 round-to-nearest-even, bit carrier = short
static __device__ __forceinline__ short f2bf(float f) {
  union { float f; unsigned u; } x; x.f = f;
  unsigned r = x.u + 0x7FFFu + ((x.u >> 16) & 1u);
  return (short)(r >> 16);
}

// bf16 vs fp32 input sniff (see round-1 notes). 16-of-32 exponent vote.
static __device__ __forceinline__ bool sniff_is_bf16(const unsigned* __restrict__ x) {
  int cnt = 0;
#pragma unroll
  for (int i = 0; i < 32; ++i) {
    unsigned e = (x[i] >> 7) & 0xFFu;
    cnt += (e >= 0x70u && e <= 0x8Fu) ? 1 : 0;
  }
  return cnt >= 16;
}

static __device__ __forceinline__ short8 load8f32(const char* p, size_t idx) {
  const float4* f = (const float4*)(p + idx * 4);
  float4 a = f[0], b = f[1];
  short8 r;
  r[0] = f2bf(a.x); r[1] = f2bf(a.y); r[2] = f2bf(a.z); r[3] = f2bf(a.w);
  r[4] = f2bf(b.x); r[5] = f2bf(b.y); r[6] = f2bf(b.z); r[7] = f2bf(b.w);
  return r;
}

// ---- preprocessing: x -> bf16 copy/convert --------------------------------
__global__ __launch_bounds__(256) void conv_x(const char* __restrict__ x,
                                              short* __restrict__ o, int n,
                                              const unsigned* __restrict__ xs) {
  const bool isbf = sniff_is_bf16(xs);
  const int i = (blockIdx.x * 256 + threadIdx.x) * 8;
  if (i >= n) return;
  if (isbf) *(short8*)(o + i) = *(const short8*)((const short*)x + i);
  else      *(short8*)(o + i) = load8f32(x, (size_t)i);
}

// ---- preprocessing: W [K][N] -> W^T [N][K] bf16 ---------------------------
__global__ __launch_bounds__(256) void tpose(const char* __restrict__ w,
                                             short* __restrict__ wt, int K, int N,
                                             const unsigned* __restrict__ xs) {
  const bool isbf = sniff_is_bf16(xs);
  __shared__ short tile[32][33];
  const int n0 = blockIdx.x * 32, k0 = blockIdx.y * 32;
  const int tx = threadIdx.x & 31, ty = threadIdx.x >> 5;  // 32 x 8
#pragma unroll
  for (int i = 0; i < 4; ++i) {
    const int r = ty * 4 + i;
    const size_t off = (size_t)(k0 + r) * N + n0 + tx;
    tile[r][tx] = isbf ? ((const short*)w)[off] : f2bf(((const float*)w)[off]);
  }
  __syncthreads();
#pragma unroll
  for (int i = 0; i < 4; ++i) {
    const int r = ty * 4 + i;
    wt[(size_t)(n0 + r) * K + k0 + tx] = tile[tx][r];
  }
}

// ---- m97-style GEMM: C[M,N] = A[M,K] @ Bt[N,K]^T, bf16 in, fp32 accum -----
// 128x128 tile, BK=32, 256 thr = 4 waves, each wave owns a 64x64 quadrant.
// Staging via global_load_lds width=16 (wave-uniform LDS base + lane*16).
__global__ __launch_bounds__(256) void gemm128(const short* __restrict__ A,
                                               const short* __restrict__ Bt,
                                               void* __restrict__ C,
                                               int M, int N, int K,
                                               int dynout,
                                               const unsigned* __restrict__ xs) {
  // out dtype: dynout ? (sniff: bf16 in -> bf16 out, else fp32) : bf16 ws
  const bool out_f32 = dynout ? !sniff_is_bf16(xs) : false;

  __shared__ short as[128 * 32];
  __shared__ short bs[128 * 32];
  const int tid = threadIdx.x;
  const int wid = tid >> 6, lane = tid & 63;
  const int quad = lane >> 4, l16 = lane & 15;
  const int wm = wid >> 1, wn = wid & 1;
  const int m0 = blockIdx.y * 128, n0 = blockIdx.x * 128;

  // staging map: round r covers rows [r*64, r*64+64); lane l -> row +l/4, kc (l%4)*8
  const int srow = wid * 16 + (lane >> 2);
  const int skc = (lane & 3) * 8;

  const floatx4 zero4 = {0.f, 0.f, 0.f, 0.f};
  floatx4 acc[4][4];
#pragma unroll
  for (int i = 0; i < 4; ++i)
#pragma unroll
    for (int j = 0; j < 4; ++j) acc[i][j] = zero4;

  for (int kt = 0; kt < K; kt += 32) {
    __syncthreads();  // previous iter's LDS readers done
#pragma unroll
    for (int r = 0; r < 2; ++r) {
      const short* ga = A + (size_t)(m0 + r * 64 + srow) * K + kt + skc;
      const short* gb = Bt + (size_t)(n0 + r * 64 + srow) * K + kt + skc;
      __builtin_amdgcn_global_load_lds(GLB_CAST(ga), LDS_CAST(as + r * 2048 + wid * 512), 16, 0, 0);
      __builtin_amdgcn_global_load_lds(GLB_CAST(gb), LDS_CAST(bs + r * 2048 + wid * 512), 16, 0, 0);
    }
    __syncthreads();  // loads visible (compiler drains vmcnt before barrier)

    short8 afr[4], bfr[4];
#pragma unroll
    for (int mt = 0; mt < 4; ++mt)
      afr[mt] = *(const short8*)&as[(wm * 64 + mt * 16 + l16) * 32 + quad * 8];
#pragma unroll
    for (int nt = 0; nt < 4; ++nt)
      bfr[nt] = *(const short8*)&bs[(wn * 64 + nt * 16 + l16) * 32 + quad * 8];
#pragma unroll
    for (int mt = 0; mt < 4; ++mt)
#pragma unroll
      for (int nt = 0; nt < 4; ++nt)
        acc[mt][nt] = mfma_bf16(afr[mt], bfr[nt], acc[mt][nt]);
  }

  // epilogue: C row = quad*4+r, col = l16 within each 16x16 tile
  const int row0 = m0 + wm * 64 + quad * 4;
  const int col0 = n0 + wn * 64 + l16;
#pragma unroll
  for (int mt = 0; mt < 4; ++mt)
#pragma unroll
    for (int nt = 0; nt < 4; ++nt)
#pragma unroll
      for (int r = 0; r < 4; ++r) {
        const size_t off = (size_t)(row0 + mt * 16 + r) * N + col0 + nt * 16;
        if (out_f32) ((float*)C)[off] = acc[mt][nt][r];
        else         ((short*)C)[off] = f2bf(acc[mt][nt][r]);
      }
}

// ---- flash-style causal attention (unchanged from round 2, validated) -----
__global__ __launch_bounds__(256) void attn(const short* __restrict__ qkv,
                                            short* __restrict__ y) {
  __shared__ short vt[64][40];     // V^T tile: [d][key]
  __shared__ short ps[4][16][40];  // per-wave P: [q][key]
  const int tid = threadIdx.x;
  const int wid = tid >> 6, lane = tid & 63;
  const int quad = lane >> 4, l16 = lane & 15;
  const int b = blockIdx.x >> 4, h = blockIdx.x & 15;
  const int q0 = blockIdx.y * 64;
  const int qw0 = q0 + wid * 16;

  const short* base = qkv + (size_t)b * T_SEQ * CQKV + h * DHEAD;

  short8 aq[2];
#pragma unroll
  for (int kc = 0; kc < 2; ++kc)
    aq[kc] = *(const short8*)(base + (size_t)(qw0 + l16) * CQKV + kc * 32 + quad * 8);

  const floatx4 zero4 = {0.f, 0.f, 0.f, 0.f};
  floatx4 o[4];
#pragma unroll
  for (int i = 0; i < 4; ++i) o[i] = zero4;
  float mrow[4] = {-INFINITY, -INFINITY, -INFINITY, -INFINITY};
  float lrow[4] = {0.f, 0.f, 0.f, 0.f};

  const int vkey = tid >> 3, vd = (tid & 7) * 8;
  const int kend = q0 + 64;

  for (int kt = 0; kt < kend; kt += 32) {
    __syncthreads();
    {
      short8 vv = *(const short8*)(base + (size_t)(kt + vkey) * CQKV + 2 * DMODEL + vd);
#pragma unroll
      for (int j = 0; j < 8; ++j) vt[vd + j][vkey] = vv[j];
    }
    __syncthreads();

    floatx4 s[2] = {zero4, zero4};
#pragma unroll
    for (int nt = 0; nt < 2; ++nt)
#pragma unroll
      for (int kc = 0; kc < 2; ++kc) {
        short8 bkf = *(const short8*)(base + (size_t)(kt + nt * 16 + l16) * CQKV +
                                      DMODEL + kc * 32 + quad * 8);
        s[nt] = mfma_bf16(aq[kc], bkf, s[nt]);
      }

#pragma unroll
    for (int nt = 0; nt < 2; ++nt)
#pragma unroll
      for (int r = 0; r < 4; ++r) {
        const int key = kt + nt * 16 + l16;
        const int q = qw0 + quad * 4 + r;
        const float v = s[nt][r] * 0.125f;
        s[nt][r] = (key <= q) ? v : -INFINITY;
      }

    float alpha[4];
#pragma unroll
    for (int r = 0; r < 4; ++r) {
      float mx = fmaxf(s[0][r], s[1][r]);
      mx = fmaxf(mx, __shfl_xor(mx, 1, 16));
      mx = fmaxf(mx, __shfl_xor(mx, 2, 16));
      mx = fmaxf(mx, __shfl_xor(mx, 4, 16));
      mx = fmaxf(mx, __shfl_xor(mx, 8, 16));
      const float nm = fmaxf(mrow[r], mx);
      alpha[r] = __expf(mrow[r] - nm);
      mrow[r] = nm;
    }
#pragma unroll
    for (int nt = 0; nt < 2; ++nt)
#pragma unroll
      for (int r = 0; r < 4; ++r)
        s[nt][r] = __expf(s[nt][r] - mrow[r]);

#pragma unroll
    for (int r = 0; r < 4; ++r) {
      float rs = s[0][r] + s[1][r];
      rs += __shfl_xor(rs, 1, 16);
      rs += __shfl_xor(rs, 2, 16);
      rs += __shfl_xor(rs, 4, 16);
      rs += __shfl_xor(rs, 8, 16);
      lrow[r] = lrow[r] * alpha[r] + rs;
    }

#pragma unroll
    for (int d4 = 0; d4 < 4; ++d4)
#pragma unroll
      for (int r = 0; r < 4; ++r) o[d4][r] *= alpha[r];

#pragma unroll
    for (int nt = 0; nt < 2; ++nt)
#pragma unroll
      for (int r = 0; r < 4; ++r)
        ps[wid][quad * 4 + r][nt * 16 + l16] = f2bf(s[nt][r]);

    __syncthreads();

    short8 ap = *(const short8*)&ps[wid][l16][quad * 8];
#pragma unroll
    for (int d4 = 0; d4 < 4; ++d4) {
      short8 bvf = *(const short8*)&vt[d4 * 16 + l16][quad * 8];
      o[d4] = mfma_bf16(ap, bvf, o[d4]);
    }
  }

#pragma unroll
  for (int d4 = 0; d4 < 4; ++d4)
#pragma unroll
    for (int r = 0; r < 4; ++r) {
      const int q = qw0 + quad * 4 + r;
      y[(size_t)(b * T_SEQ + q) * DMODEL + h * DHEAD + d4 * 16 + l16] =
          f2bf(o[d4][r] / lrow[r]);
    }
}

extern "C" void kernel_launch(void* const* d_in, const int* in_sizes, int n_in,
                              void* d_out, int out_size, void* d_ws, size_t ws_size,
                              hipStream_t stream) {
  const char* x = (const char*)d_in[0];       // [4,2048,1024] fp32 (or bf16)
  const char* w_qkv = (const char*)d_in[1];   // [1024,3072]
  const char* w_proj = (const char*)d_in[2];  // [1024,1024]
  const unsigned* xs = (const unsigned*)d_in[0];

  // ws layout (75.5 MB): qkv | wqkvT | wprojT | xbf (aliased with ybuf)
  short* qkv = (short*)d_ws;                         // 8192*3072
  short* wqkvT = qkv + (size_t)8192 * 3072;          // 3072*1024
  short* wprojT = wqkvT + (size_t)3072 * 1024;       // 1024*1024
  short* xbf = wprojT + (size_t)1024 * 1024;         // 8192*1024
  short* ybuf = xbf;                                 // alias: xbf dead after gemm1

  // 0) preprocess: x -> bf16; weights -> transposed bf16
  conv_x<<<8192 * 1024 / (256 * 8), 256, 0, stream>>>(x, xbf, 8192 * 1024, xs);
  {
    dim3 g1(3072 / 32, 1024 / 32);
    tpose<<<g1, 256, 0, stream>>>(w_qkv, wqkvT, 1024, 3072, xs);
    dim3 g2(1024 / 32, 1024 / 32);
    tpose<<<g2, 256, 0, stream>>>(w_proj, wprojT, 1024, 1024, xs);
  }
  // 1) qkv = xbf @ wqkvT^T   (M=8192, N=3072, K=1024), bf16 out
  {
    dim3 grid(3072 / 128, 8192 / 128);
    gemm128<<<grid, 256, 0, stream>>>(xbf, wqkvT, qkv, 8192, 3072, 1024, 0, xs);
  }
  // 2) attention
  {
    dim3 grid(4 * NHEADS, T_SEQ / 64);
    attn<<<grid, 256, 0, stream>>>(qkv, ybuf);
  }
  // 3) out = ybuf @ wprojT^T (M=8192, N=1024, K=1024), out dtype per sniff
  {
    dim3 grid(1024 / 128, 8192 / 128);
    gemm128<<<grid, 256, 0, stream>>>(ybuf, wprojT, d_out, 8192, 1024, 1024, 1, xs);
  }
}

// Round 4
// 335.178 us; speedup vs baseline: 2.0119x; 1.3622x over previous
//
#include <hip/hip_runtime.h>
#include <hip/hip_bf16.h>
#include <cmath>

#define T_SEQ 2048
#define NHEADS 16
#define DHEAD 64
#define DMODEL 1024
#define CQKV 3072

typedef __attribute__((ext_vector_type(8))) short short8;
typedef __attribute__((ext_vector_type(8))) __bf16 bf16x8;
typedef __attribute__((ext_vector_type(2))) __bf16 bf16x2;
typedef __attribute__((ext_vector_type(4))) float floatx4;
typedef __attribute__((ext_vector_type(2))) unsigned uint2v;

#define LDS_CAST(p) ((__attribute__((address_space(3))) void*)(p))
#define GLB_CAST(p) ((const __attribute__((address_space(1))) void*)(p))

static __device__ __forceinline__ floatx4 mfma_bf16(short8 a, short8 b, floatx4 c) {
  return __builtin_amdgcn_mfma_f32_16x16x32_bf16(
      __builtin_bit_cast(bf16x8, a), __builtin_bit_cast(bf16x8, b), c, 0, 0, 0);
}

// fp32 -> bf16 round-to-nearest-even, bit carrier = short
static __device__ __forceinline__ short f2bf(float f) {
  union { float f; unsigned u; } x; x.f = f;
  unsigned r = x.u + 0x7FFFu + ((x.u >> 16) & 1u);
  return (short)(r >> 16);
}

// pack 2 fp32 -> 2 bf16 in one b32 (HW cvt_pk when available)
static __device__ __forceinline__ unsigned pk2bf(float a, float b) {
#if __has_builtin(__builtin_amdgcn_cvt_pk_bf16_f32)
  return __builtin_bit_cast(unsigned, __builtin_amdgcn_cvt_pk_bf16_f32(a, b));
#else
  return (unsigned)(unsigned short)f2bf(a) | ((unsigned)(unsigned short)f2bf(b) << 16);
#endif
}

static __device__ __forceinline__ float exp2_(float x) {
#if __has_builtin(__builtin_amdgcn_exp2f)
  return __builtin_amdgcn_exp2f(x);
#else
  return exp2f(x);
#endif
}

// bf16 vs fp32 input sniff (round-1 notes). 16-of-32 exponent vote.
static __device__ __forceinline__ bool sniff_is_bf16(const unsigned* __restrict__ x) {
  int cnt = 0;
#pragma unroll
  for (int i = 0; i < 32; ++i) {
    unsigned e = (x[i] >> 7) & 0xFFu;
    cnt += (e >= 0x70u && e <= 0x8Fu) ? 1 : 0;
  }
  return cnt >= 16;
}

static __device__ __forceinline__ short8 load8f32(const char* p, size_t idx) {
  const float4* f = (const float4*)(p + idx * 4);
  float4 a = f[0], b = f[1];
  short8 r;
  r[0] = f2bf(a.x); r[1] = f2bf(a.y); r[2] = f2bf(a.z); r[3] = f2bf(a.w);
  r[4] = f2bf(b.x); r[5] = f2bf(b.y); r[6] = f2bf(b.z); r[7] = f2bf(b.w);
  return r;
}

// ---- preprocessing: x -> bf16 copy/convert --------------------------------
__global__ __launch_bounds__(256) void conv_x(const char* __restrict__ x,
                                              short* __restrict__ o, int n,
                                              const unsigned* __restrict__ xs) {
  const bool isbf = sniff_is_bf16(xs);
  const int i = (blockIdx.x * 256 + threadIdx.x) * 8;
  if (i >= n) return;
  if (isbf) *(short8*)(o + i) = *(const short8*)((const short*)x + i);
  else      *(short8*)(o + i) = load8f32(x, (size_t)i);
}

// ---- preprocessing: W [K][N] -> W^T [N][K] bf16 ---------------------------
__global__ __launch_bounds__(256) void tpose(const char* __restrict__ w,
                                             short* __restrict__ wt, int K, int N,
                                             const unsigned* __restrict__ xs) {
  const bool isbf = sniff_is_bf16(xs);
  __shared__ short tile[32][33];
  const int n0 = blockIdx.x * 32, k0 = blockIdx.y * 32;
  const int tx = threadIdx.x & 31, ty = threadIdx.x >> 5;  // 32 x 8
#pragma unroll
  for (int i = 0; i < 4; ++i) {
    const int r = ty * 4 + i;
    const size_t off = (size_t)(k0 + r) * N + n0 + tx;
    tile[r][tx] = isbf ? ((const short*)w)[off] : f2bf(((const float*)w)[off]);
  }
  __syncthreads();
#pragma unroll
  for (int i = 0; i < 4; ++i) {
    const int r = ty * 4 + i;
    wt[(size_t)(n0 + r) * K + k0 + tx] = tile[tx][r];
  }
}

// ---- m97-style GEMM (validated round 3): C = A @ Bt^T ---------------------
__global__ __launch_bounds__(256) void gemm128(const short* __restrict__ A,
                                               const short* __restrict__ Bt,
                                               void* __restrict__ C,
                                               int M, int N, int K,
                                               int dynout,
                                               const unsigned* __restrict__ xs) {
  const bool out_f32 = dynout ? !sniff_is_bf16(xs) : false;

  __shared__ short as[128 * 32];
  __shared__ short bs[128 * 32];
  const int tid = threadIdx.x;
  const int wid = tid >> 6, lane = tid & 63;
  const int quad = lane >> 4, l16 = lane & 15;
  const int wm = wid >> 1, wn = wid & 1;
  const int m0 = blockIdx.y * 128, n0 = blockIdx.x * 128;

  const int srow = wid * 16 + (lane >> 2);
  const int skc = (lane & 3) * 8;

  const floatx4 zero4 = {0.f, 0.f, 0.f, 0.f};
  floatx4 acc[4][4];
#pragma unroll
  for (int i = 0; i < 4; ++i)
#pragma unroll
    for (int j = 0; j < 4; ++j) acc[i][j] = zero4;

  for (int kt = 0; kt < K; kt += 32) {
    __syncthreads();
#pragma unroll
    for (int r = 0; r < 2; ++r) {
      const short* ga = A + (size_t)(m0 + r * 64 + srow) * K + kt + skc;
      const short* gb = Bt + (size_t)(n0 + r * 64 + srow) * K + kt + skc;
      __builtin_amdgcn_global_load_lds(GLB_CAST(ga), LDS_CAST(as + r * 2048 + wid * 512), 16, 0, 0);
      __builtin_amdgcn_global_load_lds(GLB_CAST(gb), LDS_CAST(bs + r * 2048 + wid * 512), 16, 0, 0);
    }
    __syncthreads();

    short8 afr[4], bfr[4];
#pragma unroll
    for (int mt = 0; mt < 4; ++mt)
      afr[mt] = *(const short8*)&as[(wm * 64 + mt * 16 + l16) * 32 + quad * 8];
#pragma unroll
    for (int nt = 0; nt < 4; ++nt)
      bfr[nt] = *(const short8*)&bs[(wn * 64 + nt * 16 + l16) * 32 + quad * 8];
#pragma unroll
    for (int mt = 0; mt < 4; ++mt)
#pragma unroll
      for (int nt = 0; nt < 4; ++nt)
        acc[mt][nt] = mfma_bf16(afr[mt], bfr[nt], acc[mt][nt]);
  }

  const int row0 = m0 + wm * 64 + quad * 4;
  const int col0 = n0 + wn * 64 + l16;
#pragma unroll
  for (int mt = 0; mt < 4; ++mt)
#pragma unroll
    for (int nt = 0; nt < 4; ++nt)
#pragma unroll
      for (int r = 0; r < 4; ++r) {
        const size_t off = (size_t)(row0 + mt * 16 + r) * N + col0 + nt * 16;
        if (out_f32) ((float*)C)[off] = acc[mt][nt][r];
        else         ((short*)C)[off] = f2bf(acc[mt][nt][r]);
      }
}

// ---- flash attention, BK=64, K via global_load_lds, exp2 softmax ----------
__global__ __launch_bounds__(256) void attn(const short* __restrict__ qkv,
                                            short* __restrict__ y) {
  __shared__ short ks[64 * 64];   // [key][d], rows 128B (global_load_lds layout)
  __shared__ short vt[64][72];    // [d][key] pairs packed; stride 36 words, 16B-aligned rows
  __shared__ short ps[64][68];    // P^T [key][q]; stride 34 words, 8B-aligned cols
  const int tid = threadIdx.x;
  const int wid = tid >> 6, lane = tid & 63;
  const int quad = lane >> 4, l16 = lane & 15;
  const int b = blockIdx.x >> 4, h = blockIdx.x & 15;
  const int q0 = ((int)gridDim.y - 1 - (int)blockIdx.y) * 64;  // heavy blocks first
  const int qw0 = q0 + wid * 16;

  const short* base = qkv + (size_t)b * T_SEQ * CQKV + h * DHEAD;
  const float SC = 0.18033688011112042f;  // 0.125 * log2(e)

  // Q fragments (A-layout): m=l16 (query), k=quad*8+j (d)
  short8 aq[2];
#pragma unroll
  for (int kc = 0; kc < 2; ++kc)
    aq[kc] = *(const short8*)(base + (size_t)(qw0 + l16) * CQKV + kc * 32 + quad * 8);

  const floatx4 zero4 = {0.f, 0.f, 0.f, 0.f};
  floatx4 o[4];
#pragma unroll
  for (int i = 0; i < 4; ++i) o[i] = zero4;
  float m2[4] = {-INFINITY, -INFINITY, -INFINITY, -INFINITY};
  float lsum[4] = {0.f, 0.f, 0.f, 0.f};

  // V staging: thread covers key pair (2*kpair, 2*kpair+1) x d [vdc, vdc+8)
  const int kpair = tid & 31, vdc = (tid >> 5) * 8;
  int* vtw = (int*)vt;

  const int kend = q0 + 64;
  for (int kt = 0; kt < kend; kt += 64) {
    __syncthreads();  // prev iteration's LDS readers done
    // stage K tile: wave wid stages rows [wid*16, wid*16+16), 2 issues of 8 rows
#pragma unroll
    for (int i = 0; i < 2; ++i) {
      const short* g = base + (size_t)(kt + wid * 16 + i * 8 + (lane >> 3)) * CQKV +
                       DMODEL + (lane & 7) * 8;
      __builtin_amdgcn_global_load_lds(GLB_CAST(g),
                                       LDS_CAST(ks + (wid * 16 + i * 8) * 64), 16, 0, 0);
    }
    // stage V transposed, key pairs packed in b32
    {
      const short8 v0 = *(const short8*)(base + (size_t)(kt + 2 * kpair) * CQKV + 2 * DMODEL + vdc);
      const short8 v1 = *(const short8*)(base + (size_t)(kt + 2 * kpair + 1) * CQKV + 2 * DMODEL + vdc);
#pragma unroll
      for (int j = 0; j < 8; ++j) {
        const unsigned pk = (unsigned)(unsigned short)v0[j] | ((unsigned)(unsigned short)v1[j] << 16);
        vtw[(vdc + j) * 36 + kpair] = (int)pk;
      }
    }
    __syncthreads();

    // S = Q K^T : 16q x 64key per wave (4 nt x 2 kc MFMAs)
    floatx4 s[4];
#pragma unroll
    for (int nt = 0; nt < 4; ++nt) {
      s[nt] = zero4;
#pragma unroll
      for (int kc = 0; kc < 2; ++kc) {
        const short8 bk = *(const short8*)&ks[(nt * 16 + l16) * 64 + kc * 32 + quad * 8];
        s[nt] = mfma_bf16(aq[kc], bk, s[nt]);
      }
    }

    // scale into log2 domain; mask only on the (rare) diagonal iteration
    if (kt + 63 <= qw0) {  // wave-uniform: fully unmasked
#pragma unroll
      for (int nt = 0; nt < 4; ++nt)
#pragma unroll
        for (int r = 0; r < 4; ++r) s[nt][r] *= SC;
    } else {
#pragma unroll
      for (int nt = 0; nt < 4; ++nt)
#pragma unroll
        for (int r = 0; r < 4; ++r) {
          const int key = kt + nt * 16 + l16;
          const int q = qw0 + quad * 4 + r;
          s[nt][r] = (key <= q) ? s[nt][r] * SC : -INFINITY;
        }
    }

    // online softmax (log2 domain), row r in the 16 lanes of one quad
    float alpha[4];
#pragma unroll
    for (int r = 0; r < 4; ++r) {
      float mx = fmaxf(fmaxf(s[0][r], s[1][r]), fmaxf(s[2][r], s[3][r]));
      mx = fmaxf(mx, __shfl_xor(mx, 1, 16));
      mx = fmaxf(mx, __shfl_xor(mx, 2, 16));
      mx = fmaxf(mx, __shfl_xor(mx, 4, 16));
      mx = fmaxf(mx, __shfl_xor(mx, 8, 16));
      const float nm = fmaxf(m2[r], mx);
      alpha[r] = exp2_(m2[r] - nm);
      m2[r] = nm;
    }
#pragma unroll
    for (int nt = 0; nt < 4; ++nt)
#pragma unroll
      for (int r = 0; r < 4; ++r) s[nt][r] = exp2_(s[nt][r] - m2[r]);

#pragma unroll
    for (int r = 0; r < 4; ++r) {
      float t = (s[0][r] + s[1][r]) + (s[2][r] + s[3][r]);
      t += __shfl_xor(t, 1, 16);
      t += __shfl_xor(t, 2, 16);
      t += __shfl_xor(t, 4, 16);
      t += __shfl_xor(t, 8, 16);
      lsum[r] = lsum[r] * alpha[r] + t;
    }
#pragma unroll
    for (int d4 = 0; d4 < 4; ++d4)
#pragma unroll
      for (int r = 0; r < 4; ++r) o[d4][r] *= alpha[r];

    // P^T -> LDS: lane writes 4 rows (quad*4..+3) for key nt*16+l16, packed b64
#pragma unroll
    for (int nt = 0; nt < 4; ++nt) {
      uint2v w;
      w[0] = pk2bf(s[nt][0], s[nt][1]);
      w[1] = pk2bf(s[nt][2], s[nt][3]);
      *(uint2v*)&ps[nt * 16 + l16][wid * 16 + quad * 4] = w;
    }
    // wave-internal write->read on own q-columns: DS ops are in-order per wave

    // O += P V : A-frag from ps (d16 scalar reads), B-frag from vt (b128)
#pragma unroll
    for (int koff = 0; koff < 64; koff += 32) {
      short8 ap;
#pragma unroll
      for (int j = 0; j < 8; ++j)
        ap[j] = ps[koff + quad * 8 + j][wid * 16 + l16];
#pragma unroll
      for (int d4 = 0; d4 < 4; ++d4) {
        const short8 bv = *(const short8*)&vt[d4 * 16 + l16][koff + quad * 8];
        o[d4] = mfma_bf16(ap, bv, o[d4]);
      }
    }
  }

  // epilogue: O /= l, write y[b, q, h*64 + d]
  float rl[4];
#pragma unroll
  for (int r = 0; r < 4; ++r) rl[r] = 1.0f / lsum[r];
#pragma unroll
  for (int d4 = 0; d4 < 4; ++d4)
#pragma unroll
    for (int r = 0; r < 4; ++r) {
      const int q = qw0 + quad * 4 + r;
      y[(size_t)(b * T_SEQ + q) * DMODEL + h * DHEAD + d4 * 16 + l16] =
          f2bf(o[d4][r] * rl[r]);
    }
}

extern "C" void kernel_launch(void* const* d_in, const int* in_sizes, int n_in,
                              void* d_out, int out_size, void* d_ws, size_t ws_size,
                              hipStream_t stream) {
  const char* x = (const char*)d_in[0];       // [4,2048,1024] fp32 (or bf16)
  const char* w_qkv = (const char*)d_in[1];   // [1024,3072]
  const char* w_proj = (const char*)d_in[2];  // [1024,1024]
  const unsigned* xs = (const unsigned*)d_in[0];

  short* qkv = (short*)d_ws;                         // 8192*3072
  short* wqkvT = qkv + (size_t)8192 * 3072;          // 3072*1024
  short* wprojT = wqkvT + (size_t)3072 * 1024;       // 1024*1024
  short* xbf = wprojT + (size_t)1024 * 1024;         // 8192*1024
  short* ybuf = xbf;                                 // alias: xbf dead after gemm1

  conv_x<<<8192 * 1024 / (256 * 8), 256, 0, stream>>>(x, xbf, 8192 * 1024, xs);
  {
    dim3 g1(3072 / 32, 1024 / 32);
    tpose<<<g1, 256, 0, stream>>>(w_qkv, wqkvT, 1024, 3072, xs);
    dim3 g2(1024 / 32, 1024 / 32);
    tpose<<<g2, 256, 0, stream>>>(w_proj, wprojT, 1024, 1024, xs);
  }
  {
    dim3 grid(3072 / 128, 8192 / 128);
    gemm128<<<grid, 256, 0, stream>>>(xbf, wqkvT, qkv, 8192, 3072, 1024, 0, xs);
  }
  {
    dim3 grid(4 * NHEADS, T_SEQ / 64);
    attn<<<grid, 256, 0, stream>>>(qkv, ybuf);
  }
  {
    dim3 grid(1024 / 128, 8192 / 128);
    gemm128<<<grid, 256, 0, stream>>>(ybuf, wprojT, d_out, 8192, 1024, 1024, 1, xs);
  }
}